// Round 12
// baseline (142.963 us; speedup 1.0000x reference)
//
#include <hip/hip_runtime.h>
#include <math.h>

#define NSAMP 32768
#define NFFT2 65536
#define NFRM 128
#define PSTRIDE 2688
#define P_FEPAIR 64
#define P_PW2 320
#define P_LQ 1344
#define P_AF 1604
#define P_END 2636
#define TWO_PI_F 6.28318530717958647692f

typedef float2 cplx;

__device__ __forceinline__ cplx cmul_(cplx a, cplx b){ return make_float2(a.x*b.x - a.y*b.y, a.x*b.y + a.y*b.x); }
__device__ __forceinline__ cplx cadd_(cplx a, cplx b){ return make_float2(a.x+b.x, a.y+b.y); }
__device__ __forceinline__ cplx csub_(cplx a, cplx b){ return make_float2(a.x-b.x, a.y-b.y); }

__device__ __forceinline__ unsigned int packbf2(float re, float im){
  unsigned int ur = __float_as_uint(re);
  unsigned int ui = __float_as_uint(im);
  ur = (ur + 0x7FFFu + ((ur>>16)&1u)) >> 16;
  ui = (ui + 0x7FFFu + ((ui>>16)&1u)) & 0xFFFF0000u;
  return ur | ui;
}
__device__ __forceinline__ float ubf_lo(unsigned int u){ return __uint_as_float(u<<16); }
__device__ __forceinline__ float ubf_hi(unsigned int u){ return __uint_as_float(u & 0xFFFF0000u); }

template<bool INV>
__device__ __forceinline__ void dft4_(cplx x0,cplx x1,cplx x2,cplx x3, cplx&y0,cplx&y1,cplx&y2,cplx&y3){
  cplx t0=cadd_(x0,x2), t1=csub_(x0,x2), t2=cadd_(x1,x3), t3=csub_(x1,x3);
  y0=cadd_(t0,t2); y2=csub_(t0,t2);
  cplx it3 = make_float2(-t3.y, t3.x);
  if (INV){ y1=cadd_(t1,it3); y3=csub_(t1,it3); }
  else    { y1=csub_(t1,it3); y3=cadd_(t1,it3); }
}

template<bool INV>
__device__ __forceinline__ void dft8ip_(cplx* v){
  cplx e0,e1,e2,e3,o0,o1,o2,o3;
  dft4_<INV>(v[0],v[2],v[4],v[6], e0,e1,e2,e3);
  dft4_<INV>(v[1],v[3],v[5],v[7], o0,o1,o2,o3);
  const float r = 0.70710678118654752440f;
  cplx w1 = INV ? make_float2(r, r)    : make_float2(r,-r);
  cplx w2 = INV ? make_float2(0.f,1.f) : make_float2(0.f,-1.f);
  cplx w3 = INV ? make_float2(-r,r)    : make_float2(-r,-r);
  cplx t1 = cmul_(o1,w1), t2 = cmul_(o2,w2), t3 = cmul_(o3,w3);
  v[0]=cadd_(e0,o0); v[4]=csub_(e0,o0);
  v[1]=cadd_(e1,t1); v[5]=csub_(e1,t1);
  v[2]=cadd_(e2,t2); v[6]=csub_(e2,t2);
  v[3]=cadd_(e3,t3); v[7]=csub_(e3,t3);
}

template<bool INV>
__device__ __forceinline__ void dft16ip_(cplx* v){
  cplx t0[4], t1[4], t2[4], t3[4];
  dft4_<INV>(v[0], v[4], v[8],  v[12], t0[0],t0[1],t0[2],t0[3]);
  dft4_<INV>(v[1], v[5], v[9],  v[13], t1[0],t1[1],t1[2],t1[3]);
  dft4_<INV>(v[2], v[6], v[10], v[14], t2[0],t2[1],t2[2],t2[3]);
  dft4_<INV>(v[3], v[7], v[11], v[15], t3[0],t3[1],t3[2],t3[3]);
  const float C1=0.92387953251128675613f, S1=0.38268343236508977172f, R2=0.70710678118654752440f;
  #define TWD_(x, cc, ss) (INV ? cmul_((x), make_float2((cc), (ss))) : cmul_((x), make_float2((cc), -(ss))))
  t1[1] = TWD_(t1[1], C1, S1);
  t1[2] = TWD_(t1[2], R2, R2);
  t1[3] = TWD_(t1[3], S1, C1);
  t2[1] = TWD_(t2[1], R2, R2);
  t2[2] = TWD_(t2[2], 0.f, 1.f);
  t2[3] = TWD_(t2[3], -R2, R2);
  t3[1] = TWD_(t3[1], S1, C1);
  t3[2] = TWD_(t3[2], -R2, R2);
  t3[3] = TWD_(t3[3], -C1, -S1);
  #undef TWD_
  dft4_<INV>(t0[0], t1[0], t2[0], t3[0], v[0], v[4], v[8],  v[12]);
  dft4_<INV>(t0[1], t1[1], t2[1], t3[1], v[1], v[5], v[9],  v[13]);
  dft4_<INV>(t0[2], t1[2], t2[2], t3[2], v[2], v[6], v[10], v[14]);
  dft4_<INV>(t0[3], t1[3], t2[3], t3[3], v[3], v[7], v[11], v[15]);
}

template<int R0, bool INV>
__device__ __forceinline__ void fft_core(float* lre, float* lim, int t){
  constexpr int Q = R0/16;
  constexpr int S1 = R0 + 8;
  int g = t >> 4, a = t & 15;
  cplx v[Q];
  #pragma unroll
  for (int bb=0;bb<Q;bb++){ int idx = g*S1 + a + 16*bb; v[bb]=make_float2(lre[idx],lim[idx]); }
  if constexpr (Q==16) dft16ip_<INV>(v); else dft8ip_<INV>(v);
  float th = (INV?TWO_PI_F:-TWO_PI_F)*(float)a/(float)R0;
  float sn,cs; __sincosf(th,&sn,&cs);
  cplx w1=make_float2(cs,sn), wu=w1;
  #pragma unroll
  for (int c=1;c<Q;c++){ v[c]=cmul_(v[c],wu); wu=cmul_(wu,w1); }
  __syncthreads();
  #pragma unroll
  for (int c=0;c<Q;c++){ int m = a*Q + ((c+a)&(Q-1)); lre[g*S1+m]=v[c].x; lim[g*S1+m]=v[c].y; }
  __syncthreads();
}

template<int R0, bool INV>
__device__ __forceinline__ bool fft_stage2(const float* lre, const float* lim, int t, int& g2, int& c2, cplx* z){
  constexpr int Q = R0/16; constexpr int S1 = R0+8;
  bool active = (R0==256) || (t < 16*Q);
  g2 = (R0==256)?(t>>4):(t>>3);
  c2 = (R0==256)?(t&15):(t&7);
  if (active){
    #pragma unroll
    for (int a2=0;a2<16;a2++){ int m = a2*Q + ((c2+a2)&(Q-1)); z[a2]=make_float2(lre[g2*S1+m], lim[g2*S1+m]); }
    dft16ip_<INV>(z);
  }
  return active;
}

// ---------------- noise fwd pass1 with fused pack; bf16-packed output ----------------
__global__ __launch_bounds__(256) void k_fft_pack_fwd1(const float* __restrict__ noise, unsigned int* __restrict__ dst, float interBase){
  constexpr int Q=16, S1=264;
  __shared__ float lre[4352], lim[4352];
  int t=threadIdx.x;
  int bx=blockIdx.x;
  int sig = bx>>3;
  int tBase=(bx&7)*16;
  const float* n0 = noise + (size_t)(2*sig)*NSAMP;
  const float* n1 = noise + (size_t)(2*sig+1)*NSAMP;
  #pragma unroll
  for (int i=0;i<16;i++){
    int e=t+256*i, g=e&15, r=e>>4;
    int ts = tBase+g+128*r;
    lre[g*S1+r]=n0[ts]*2.f-1.f;
    lim[g*S1+r]=n1[ts]*2.f-1.f;
  }
  __syncthreads();
  fft_core<256,false>(lre,lim,t);
  int g2,c2; cplx z[16];
  fft_stage2<256,false>(lre,lim,t,g2,c2,z);
  int p=tBase+g2;
  float thp=interBase*(float)p;
  float snc,csc; __sincosf(thp*(float)c2,&snc,&csc);
  float sns,css; __sincosf(thp*(float)Q,&sns,&css);
  cplx wu=make_float2(csc,snc), ws=make_float2(css,sns);
  unsigned int* db = dst + (size_t)sig*NSAMP;
  size_t ob=(size_t)256*(size_t)p+(size_t)c2;
  #pragma unroll
  for (int d=0;d<16;d++){
    cplx val = cmul_(z[d],wu);
    db[ob+(size_t)(d*16)] = packbf2(val.x, val.y);
    wu=cmul_(wu,ws);
  }
}

// ---------------- noise fwd pass2 + filter + inverse pass1, all fused (bf16 input) ----------------
__device__ __forceinline__ void fft128_natural(float* re, float* im, int t){
  __syncthreads();
  fft_core<128,false>(re,im,t);
  int g2,c2; cplx z[16];
  bool act = fft_stage2<128,false>(re,im,t,g2,c2,z);
  __syncthreads();
  if (act){
    #pragma unroll
    for (int d=0;d<16;d++){ int u=c2+8*d; re[u*17+g2]=z[d].x; im[u*17+g2]=z[d].y; }
  }
  __syncthreads();
}

__global__ __launch_bounds__(256) void k_nfilter_ip1(const unsigned int* __restrict__ src, cplx* __restrict__ dst,
    const float* __restrict__ P){
  __shared__ float aRe[2176], aIm[2176], bRe[2176], bIm[2176];
  __shared__ float fRe[2176], fIm[2176];
  __shared__ float c1s[16], c2sh[16];
  int t=threadIdx.x, pb=blockIdx.x, j=blockIdx.y;
  const unsigned int* sb = src + ((size_t)j<<15);
  cplx* db = dst + ((size_t)j<<15);
  if (t<16) c1s[t] = P[(size_t)(2*j)*PSTRIDE+28+t];
  else if (t<32) c2sh[t-16] = P[(size_t)(2*j+1)*PSTRIDE+28+(t-16)];
  #pragma unroll
  for (int i=0;i<8;i++){
    int e=t+256*i, g=e&15, r=e>>4;
    int col = (pb<8)? (pb*16+g) : (g*16);
    unsigned int u = sb[col + (r<<8)];
    aRe[g*136+r]=ubf_lo(u); aIm[g*136+r]=ubf_hi(u);
  }
  fft128_natural(aRe,aIm,t);
  if (pb<8){
    #pragma unroll
    for (int i=0;i<8;i++){
      int e=t+256*i, g=e&15, r=e>>4;
      int col = 240-pb*16+g;
      unsigned int u = sb[col + (r<<8)];
      bRe[g*136+r]=ubf_lo(u); bIm[g*136+r]=ubf_hi(u);
    }
    fft128_natural(bRe,bIm,t);
  }
  const float inv32768 = 1.0f/32768.0f;
  if (pb<8){
    for (int s=0;s<2;s++){
      __syncthreads();
      #pragma unroll
      for (int uu=0; uu<8; uu++){
        int g=t&15, u=(t>>4)+16*uu;
        if (g!=0){
          int colK = s? (240-pb*16+g) : (pb*16+g);
          int gm=16-g, um=127-u;
          float Zkx,Zky,Zmx,Zmy;
          if (s==0){ Zkx=aRe[u*17+g]; Zky=aIm[u*17+g]; Zmx=bRe[um*17+gm]; Zmy=bIm[um*17+gm]; }
          else     { Zkx=bRe[u*17+g]; Zky=bIm[u*17+g]; Zmx=aRe[um*17+gm]; Zmy=aIm[um*17+gm]; }
          int k = colK + (u<<8);
          int kb = min(k, NSAMP-k);
          float coords=fminf(fmaxf((kb+0.5f)*(16.0f/16385.0f)-0.5f,0.0f),15.0f);
          int lo=(int)coords; float w=coords-lo; int hi=min(lo+1,15);
          float s1=(c1s[lo]+w*(c1s[hi]-c1s[lo]))*inv32768;
          float s2=(c2sh[lo]+w*(c2sh[hi]-c2sh[lo]))*inv32768;
          float U1x=0.5f*(Zkx+Zmx), U1y=0.5f*(Zky-Zmy);
          float U2x=0.5f*(Zky+Zmy), U2y=-0.5f*(Zkx-Zmx);
          fRe[g*136+u]=U1x*s1 - U2y*s2; fIm[g*136+u]=U1y*s1 + U2x*s2;
        }
      }
      __syncthreads();
      fft_core<128,true>(fRe,fIm,t);
      int gg,cc; cplx z[16];
      bool act = fft_stage2<128,true>(fRe,fIm,t,gg,cc,z);
      if (act && gg!=0){
        int p = (s==0) ? (pb*16+gg) : (240-pb*16+gg);
        float thp=(TWO_PI_F/32768.0f)*(float)p;
        float snc,csc; __sincosf(thp*(float)cc,&snc,&csc);
        float sns,css; __sincosf(thp*8.0f,&sns,&css);
        cplx wu=make_float2(csc,snc), wsx=make_float2(css,sns);
        int ob=128*p+cc;
        #pragma unroll
        for (int d=0;d<16;d++){ db[ob+8*d]=cmul_(z[d],wu); wu=cmul_(wu,wsx); }
      }
    }
  } else {
    __syncthreads();
    #pragma unroll
    for (int uu=0; uu<8; uu++){
      int g=t&15, u=(t>>4)+16*uu;
      int k = g*16 + (u<<8);
      int gm=(16-g)&15;
      int um=(g==0)? ((128-u)&127) : (127-u);
      float Zkx=aRe[u*17+g], Zky=aIm[u*17+g];
      float Zmx=aRe[um*17+gm], Zmy=aIm[um*17+gm];
      int kb = min(k, NSAMP-k);
      float coords=fminf(fmaxf((kb+0.5f)*(16.0f/16385.0f)-0.5f,0.0f),15.0f);
      int lo=(int)coords; float w=coords-lo; int hi=min(lo+1,15);
      float s1=(c1s[lo]+w*(c1s[hi]-c1s[lo]))*inv32768;
      float s2=(c2sh[lo]+w*(c2sh[hi]-c2sh[lo]))*inv32768;
      float U1x=0.5f*(Zkx+Zmx), U1y=0.5f*(Zky-Zmy);
      float U2x=0.5f*(Zky+Zmy), U2y=-0.5f*(Zkx-Zmx);
      fRe[g*136+u]=U1x*s1 - U2y*s2; fIm[g*136+u]=U1y*s1 + U2x*s2;
    }
    __syncthreads();
    fft_core<128,true>(fRe,fIm,t);
    int gg,cc; cplx z[16];
    bool act = fft_stage2<128,true>(fRe,fIm,t,gg,cc,z);
    if (act){
      int p = 16*gg;
      float thp=(TWO_PI_F/32768.0f)*(float)p;
      float snc,csc; __sincosf(thp*(float)cc,&snc,&csc);
      float sns,css; __sincosf(thp*8.0f,&sns,&css);
      cplx wu=make_float2(csc,snc), wsx=make_float2(css,sns);
      int ob=128*p+cc;
      #pragma unroll
      for (int d=0;d<16;d++){ db[ob+8*d]=cmul_(z[d],wu); wu=cmul_(wu,wsx); }
    }
  }
}

// ---------------- FUSED: noise inverse final + conv build + conv fwd pass1 ----------------
// grid (8 colgroups, nsigs). Phase 1: inverse final FFT of pair-signal sig -> nz written DIRECTLY
// from z-regs into nzl (17-stride bf16 tile; lre/lim overlay is only 4224 floats and must NOT
// be used for the 17-stride staging). Phase 2: two rows x two column-instances, tables overlay.
__global__ __launch_bounds__(256) void k_iconv_build(const cplx* __restrict__ B,
    const float* __restrict__ P, unsigned int* __restrict__ Cout, int sigBase, float interBase){
  constexpr int Q=16, S1=264;
  __shared__ float smem[8448];
  __shared__ unsigned int nzl[4352];     // [u<256][g<16], stride 17 (max idx 4350)
  float* lre = smem;
  float* lim = smem + 4224;
  float* sTab = smem;
  int t=threadIdx.x;
  int tBase = blockIdx.x*16;             // 0..112
  int sig = sigBase + blockIdx.y;
  // ---- phase 1: inverse final FFT (R0=256, perSig=128); z -> nzl direct ----
  {
    const cplx* sb = B + (size_t)sig*NSAMP;
    #pragma unroll
    for (int i=0;i<16;i++){
      int e=t+256*i, g=e&15, r=e>>4;
      cplx vv = sb[tBase+g + (size_t)r*128];
      lre[g*S1+r]=vv.x; lim[g*S1+r]=vv.y;
    }
    __syncthreads();
    fft_core<256,true>(lre,lim,t);
    int g2,c2; cplx z[16];
    fft_stage2<256,true>(lre,lim,t,g2,c2,z);
    // write nz tile directly from registers (no lre/lim round-trip; avoids overlay overflow)
    #pragma unroll
    for (int d=0;d<16;d++){
      int u = c2 + 16*d;                 // nz sample ts' = tBase + g2 + 128*u
      nzl[u*17+g2] = packbf2(z[d].x, z[d].y);
    }
  }
  // ---- phase 2: two rows, two column-instances each ----
  for (int rr=0; rr<2; rr++){
    int row = 2*sig + rr;
    int rowLocal = row - 2*sigBase;
    const float* Pr = P + (size_t)row*PSTRIDE;
    __syncthreads();                     // orders nzl writes / prior stage2 reads before overlay
    for (int i=t; i<P_END; i+=256) sTab[i] = Pr[i];
    __syncthreads();
    float mu=sTab[0], sigma=sTab[1], amp=sTab[2], pscale=sTab[3];
    float fac[8], mh[8];
    #pragma unroll
    for (int h=0;h<8;h++){ fac[h]=sTab[4+h]; mh[h]=sTab[12+h]; }
    const float2* fe2 = (const float2*)&sTab[P_FEPAIR];
    const float*  pw2 = &sTab[P_PW2];
    const float2* LQt = (const float2*)&sTab[P_LQ];
    const float*  Af  = &sTab[P_AF];
    float vre[2][8], vim[2][8];
    #pragma unroll
    for (int inst=0; inst<2; inst++){
      int tB = tBase + inst*128;
      #pragma unroll
      for (int i=0;i<8;i++){
        int e=t+256*i, g=e&15, r=e>>4;
        int ts = tB + g + (r<<8);
        float cc=fminf(fmaxf((ts+0.5f)*(1.0f/256.0f)-0.5f,0.0f),127.0f);
        int lo=(int)cc; float w=cc-lo;
        float2 fp = fe2[lo];
        float fev = fp.x + w*fp.y;
        int slot, n0;
        if (ts<128){ slot=0; n0=ts+1; } else { int km=(ts-128)>>8; slot=km+1; n0=ts-127-(km<<8); }
        float nf=(float)n0, nf2=nf*nf;
        float2 lq = LQt[slot];
        float base = nf*lq.x + nf2*lq.y;
        float wm = (lo<127)? w : 0.0f;
        float resv=0.f;
        #pragma unroll
        for (int h=0;h<8;h++){
          float mgb = pw2[h*128+lo];
          if (mgb > 1e-7f){
            float rv = Af[slot*8+h] + fac[h]*base;
            float fr = rv - floorf(rv);
            resv += __builtin_amdgcn_sinf(fr)*mgb*(1.0f + wm*(mh[h]-1.0f));
          }
        }
        float zz=((float)ts-mu)/sigma;
        float prb=pscale*__expf(-0.5f*zz*zz);
        unsigned int unz = nzl[(inst + 2*r)*17 + g];
        float nzv = rr ? ubf_hi(unz) : ubf_lo(unz);
        vre[inst][i] = prb*nzv*amp*fev;
        vim[inst][i] = resv;
      }
    }
    #pragma unroll
    for (int inst=0; inst<2; inst++){
      __syncthreads();
      int tB = tBase + inst*128;
      #pragma unroll
      for (int i=0;i<8;i++){
        int e=t+256*i, g=e&15, r=e>>4;
        lre[g*S1+r]=vre[inst][i]; lim[g*S1+r]=vim[inst][i];
      }
      #pragma unroll
      for (int i=8;i<16;i++){
        int e=t+256*i, g=e&15, r=e>>4;
        lre[g*S1+r]=0.f; lim[g*S1+r]=0.f;
      }
      __syncthreads();
      fft_core<256,false>(lre,lim,t);
      int g2,c2; cplx z[16];
      fft_stage2<256,false>(lre,lim,t,g2,c2,z);
      int p = tB+g2;
      float thp = interBase*(float)p;
      float snc,csc; __sincosf(thp*(float)c2,&snc,&csc);
      float sns,css; __sincosf(thp*(float)Q,&sns,&css);
      cplx wu=make_float2(csc,snc), ws=make_float2(css,sns);
      unsigned int* db = Cout + (size_t)rowLocal*NFFT2;
      size_t ob=(size_t)256*(size_t)p+(size_t)c2;
      #pragma unroll
      for (int d=0; d<16; d++){
        cplx val = cmul_(z[d],wu);
        db[ob+(size_t)(d*16)] = packbf2(val.x, val.y);
        wu=cmul_(wu,ws);
      }
    }
  }
}

// ---------------- fused: conv fwd pass2 + Z^2 accumulate (4 events) + inverse pass1; bf16 E ----------------
__global__ __launch_bounds__(256) void k_sq_inv1(const unsigned int* __restrict__ C,
    unsigned int* __restrict__ E, int bpc){
  constexpr int Q=16, S1=264;
  __shared__ float lre[4352], lim[4352];
  int t=threadIdx.x;
  int tBase = blockIdx.x*16;
  int bLoc = blockIdx.y;
  int half = blockIdx.z;
  float accx[16], accy[16];
  #pragma unroll
  for (int d=0;d<16;d++){ accx[d]=0.f; accy[d]=0.f; }
  int g2=t>>4, c2=t&15;
  for (int e=0;e<4;e++){
    int sigLoc = bLoc*8 + half*4 + e;
    const unsigned int* sb = C + (size_t)sigLoc*NFFT2;
    __syncthreads();
    #pragma unroll
    for (int i=0;i<16;i++){
      int ee=t+256*i, g=ee&15, r=ee>>4;
      unsigned int u = sb[tBase+g + (size_t)r*256];
      lre[g*S1+r]=ubf_lo(u);
      lim[g*S1+r]=ubf_hi(u);
    }
    __syncthreads();
    fft_core<256,false>(lre,lim,t);
    int gg,cc; cplx z[16];
    fft_stage2<256,false>(lre,lim,t,gg,cc,z);
    #pragma unroll
    for (int d=0;d<16;d++){
      float x=z[d].x, y=z[d].y;
      accx[d] += x*x - y*y;
      accy[d] += 2.f*x*y;
    }
  }
  __syncthreads();
  const float s = 1.0f/131072.0f;
  #pragma unroll
  for (int d=0;d<16;d++){
    int rrow = c2 + 16*d;
    lre[g2*S1+rrow] = accx[d]*s;
    lim[g2*S1+rrow] = accy[d]*s;
  }
  __syncthreads();
  fft_core<256,true>(lre,lim,t);
  int gg,cc; cplx z[16];
  fft_stage2<256,true>(lre,lim,t,gg,cc,z);
  int p = tBase+gg;
  float thp = (TWO_PI_F/65536.0f)*(float)p;
  float snc,csc; __sincosf(thp*(float)cc,&snc,&csc);
  float sns,css; __sincosf(thp*(float)Q,&sns,&css);
  cplx wu=make_float2(csc,snc), ws=make_float2(css,sns);
  unsigned int* db = E + ((size_t)half*bpc + bLoc)*NFFT2;
  size_t ob=(size_t)256*(size_t)p+(size_t)cc;
  #pragma unroll
  for (int d=0; d<16; d++){
    cplx val = cmul_(z[d],wu);
    db[ob+(size_t)(d*16)] = packbf2(val.x, val.y);
    wu=cmul_(wu,ws);
  }
}

// ---------------- conv inverse final: sum 2 bf16 partials, keep Im, write to out ----------------
__global__ __launch_bounds__(256) void k_final_imout(const unsigned int* __restrict__ E,
    float* __restrict__ out, int batchBase, int bpc){
  constexpr int S1=264;
  __shared__ float lre[4352], lim[4352];
  int t=threadIdx.x; int bx=blockIdx.x;
  int sig=bx>>4; int tBase=(bx&15)*16;
  const unsigned int* s0 = E + (size_t)sig*NFFT2;
  size_t hstride = (size_t)bpc*NFFT2;
  #pragma unroll
  for (int i=0;i<16;i++){
    int e=t+256*i, g=e&15, r=e>>4;
    size_t idx = tBase+g+(size_t)r*256;
    unsigned int u0=s0[idx], u1=s0[hstride+idx];
    lre[g*S1+r]=ubf_lo(u0)+ubf_lo(u1);
    lim[g*S1+r]=ubf_hi(u0)+ubf_hi(u1);
  }
  __syncthreads();
  fft_core<256,true>(lre,lim,t);
  int g2,c2; cplx z[16];
  fft_stage2<256,true>(lre,lim,t,g2,c2,z);
  __syncthreads();
  #pragma unroll
  for (int d=0;d<16;d++){ int u=c2+16*d; lre[u*17+g2]=z[d].y; }   // Im only
  __syncthreads();
  float* o = out + (size_t)(batchBase+sig)*NSAMP;
  #pragma unroll
  for (int i=0;i<8;i++){
    int e=t+256*i, g3=e&15, u=e>>4;
    o[tBase+g3 + u*256] = lre[u*17+g3];
  }
}

// ---------------- parameter extraction + ALL per-row tables ----------------
__global__ __launch_bounds__(256) void k_params(const float* __restrict__ x, float* __restrict__ P){
  int row = blockIdx.x; int t = threadIdx.x;
  const float* xr = x + row*428;
  float* Pr = P + (size_t)row*PSTRIDE;
  __shared__ float sx[428];
  __shared__ float fes[128], f0s[128];
  __shared__ double Cds[128];
  __shared__ float facs[8], ms[8], afs[8];
  __shared__ float f0_sh;
  for (int i=t;i<428;i+=256) sx[i]=1.0f/(1.0f+expf(-xr[i]));
  __syncthreads();
  if (t==0){
    float mean = sx[0]; float stds = sx[1]*0.1f; float amp = sx[2]*sx[2];
    float mu = fminf(fmaxf(mean*32768.0f, -16384.0f), 49152.0f);
    float sigma = fminf(fmaxf((1e-8f + stds)*32768.0f, 0.0f), 32767.0f);
    float c = 1.0f/(sigma*2.5066282746310002f);
    float tt0 = fminf(fmaxf(floorf(mu), 0.0f), 32767.0f);
    float tt1 = fminf(fmaxf(ceilf(mu), 0.0f), 32767.0f);
    float z0 = (tt0-mu)/sigma, z1=(tt1-mu)/sigma;
    float gmax = fmaxf(expf(-0.5f*z0*z0), expf(-0.5f*z1*z1));
    float pscale = c / (c*gmax + 1e-12f);
    Pr[0]=mu; Pr[1]=sigma; Pr[2]=amp; Pr[3]=pscale;
  }
  if (t<8){
    float fv = (t==0)?1.0f:(1.0f+sx[4+t]*7.0f);
    facs[t]=fv; Pr[4+t]=fv;
    float m = sx[12+t]*0.9999f; m=m*m; ms[t]=m; Pr[12+t]=m;
    afs[t]=sx[164+t]*sx[164+t];
  }
  if (t>=32&&t<48) Pr[28+(t-32)] = sx[20+(t-32)];
  if (t==64) f0_sh = sx[3]*sx[3];
  if (t==65){
    float acc=0.f;
    for (int f=0;f<128;f++){ acc += sx[36+f]*2.0f-1.0f; fes[f]=fminf(fmaxf(acc,0.f),1.f); }
  }
  __syncthreads();
  if (t<128){
    float f0=f0_sh;
    f0s[t] = f0 + sx[172+t]*(f0*0.01f);
  }
  __syncthreads();
  if (t==0){
    double acc = 128.0*(double)f0s[0]; Cds[0]=acc;
    for (int k=0;k<127;k++){ acc += 128.0*((double)f0s[k]+(double)f0s[k+1]); Cds[k+1]=acc; }
  }
  if (t<128){
    float v=fes[t], vh=fes[min(t+1,127)];
    Pr[P_FEPAIR+2*t]=v; Pr[P_FEPAIR+2*t+1]=vh-v;
  }
  if (t>=128 && t<136){
    int h=t-128; float m=ms[h];
    float acc = afs[h]*m;
    float* dstp = Pr + P_PW2 + h*128;
    dstp[0]=acc;
    for (int f=1;f<128;f++){ acc*=m; dstp[f]=acc; }
  }
  __syncthreads();
  const double MINF_D=20.0/11025.0, FSPAN_D=2980.0/11025.0;
  if (t<129){
    int k=t-1;
    float Lb, Qb;
    if (k<0){ Lb=(float)(0.5*(MINF_D+FSPAN_D*(double)f0s[0])); Qb=0.f; }
    else {
      double f0k=(double)f0s[k];
      double d=(k<127)?((double)f0s[k+1]-f0k):0.0;
      Lb=(float)(0.5*(MINF_D+FSPAN_D*f0k));
      Qb=(float)(0.5*FSPAN_D*d*(1.0/512.0));
    }
    Pr[P_LQ+2*t]=Lb; Pr[P_LQ+2*t+1]=Qb;
  }
  for (int idx=t; idx<129*8; idx+=256){
    int jj=idx>>3, h=idx&7, k=jj-1;
    float Aval;
    if (k<0) Aval=0.f;
    else {
      double phi0=(double)(128+256*k)*MINF_D+FSPAN_D*Cds[k];
      Aval=(float)(0.5*fmod((double)facs[h]*phi0,2.0));
    }
    Pr[P_AF+idx]=Aval;
  }
}

// ---------------- host ----------------
extern "C" void kernel_launch(void* const* d_in, const int* in_sizes, int n_in,
                              void* d_out, int out_size, void* d_ws, size_t ws_size,
                              hipStream_t stream){
  const float* x = (const float*)d_in[0];
  const float* noise = (const float*)d_in[1];
  float* out = (float*)d_out;
  char* ws = (char*)d_ws;

  const size_t szA = (size_t)64*NSAMP*sizeof(unsigned int);   // 8.4 MB
  const size_t szB = (size_t)64*NSAMP*sizeof(cplx);           // 16.8 MB
  const size_t szE = (size_t)2*16*NFFT2*sizeof(unsigned int); // 8.4 MB
  const size_t oA  = (size_t)2<<20;
  const size_t oB  = oA + szA;
  const size_t oE  = oB + szB;
  const size_t oC  = oE + szE;

  const int cand[5] = {1,2,4,8,16};
  int nchunk = -1;
  for (int ci=0; ci<5; ci++){
    size_t csz = ((size_t)(128/cand[ci]))*NFFT2*sizeof(unsigned int);
    if (oC + csz <= ws_size){ nchunk = cand[ci]; break; }
  }
  if (nchunk < 0) return;
  int sigPerChunk = 128/nchunk;
  int bpc = sigPerChunk/8;
  int nsigs = sigPerChunk/2;

  float* P = (float*)(ws);
  unsigned int* A = (unsigned int*)(ws + oA);
  cplx* B = (cplx*)(ws + oB);
  unsigned int* E = (unsigned int*)(ws + oE);
  unsigned int* C = (unsigned int*)(ws + oC);

  k_params<<<128, 256, 0, stream>>>(x, P);
  k_fft_pack_fwd1<<<512, 256, 0, stream>>>(noise, A, -TWO_PI_F/32768.0f);
  k_nfilter_ip1<<<dim3(9,64), 256, 0, stream>>>(A, B, P);

  for (int c=0; c<nchunk; c++){
    int sigBase = c*nsigs;
    int batchBase = c*bpc;
    k_iconv_build<<<dim3(8, nsigs), 256, 0, stream>>>(B, P, C, sigBase, -TWO_PI_F/65536.0f);
    k_sq_inv1<<<dim3(16, bpc, 2), 256, 0, stream>>>(C, E, bpc);
    k_final_imout<<<bpc*16, 256, 0, stream>>>(E, out, batchBase, bpc);
  }
}

// Round 13
// 113.133 us; speedup vs baseline: 1.2637x; 1.2637x over previous
//
#include <hip/hip_runtime.h>
#include <math.h>

#define NSAMP 32768
#define NFFT2 65536
#define NFRM 128
#define PSTRIDE 2688
#define P_FEPAIR 64
#define P_PW2 320
#define P_LQ 1344
#define P_AF 1604
#define P_END 2636
#define TWO_PI_F 6.28318530717958647692f

typedef float2 cplx;

__device__ __forceinline__ cplx cmul_(cplx a, cplx b){ return make_float2(a.x*b.x - a.y*b.y, a.x*b.y + a.y*b.x); }
__device__ __forceinline__ cplx cadd_(cplx a, cplx b){ return make_float2(a.x+b.x, a.y+b.y); }
__device__ __forceinline__ cplx csub_(cplx a, cplx b){ return make_float2(a.x-b.x, a.y-b.y); }

__device__ __forceinline__ unsigned int packbf2(float re, float im){
  unsigned int ur = __float_as_uint(re);
  unsigned int ui = __float_as_uint(im);
  ur = (ur + 0x7FFFu + ((ur>>16)&1u)) >> 16;
  ui = (ui + 0x7FFFu + ((ui>>16)&1u)) & 0xFFFF0000u;
  return ur | ui;
}
__device__ __forceinline__ float ubf_lo(unsigned int u){ return __uint_as_float(u<<16); }
__device__ __forceinline__ float ubf_hi(unsigned int u){ return __uint_as_float(u & 0xFFFF0000u); }
__device__ __forceinline__ unsigned short packbf1(float v){
  unsigned int u=__float_as_uint(v);
  return (unsigned short)((u + 0x7FFFu + ((u>>16)&1u))>>16);
}
__device__ __forceinline__ float unpackbf1(unsigned short s){ return __uint_as_float(((unsigned int)s)<<16); }

template<bool INV>
__device__ __forceinline__ void dft4_(cplx x0,cplx x1,cplx x2,cplx x3, cplx&y0,cplx&y1,cplx&y2,cplx&y3){
  cplx t0=cadd_(x0,x2), t1=csub_(x0,x2), t2=cadd_(x1,x3), t3=csub_(x1,x3);
  y0=cadd_(t0,t2); y2=csub_(t0,t2);
  cplx it3 = make_float2(-t3.y, t3.x);
  if (INV){ y1=cadd_(t1,it3); y3=csub_(t1,it3); }
  else    { y1=csub_(t1,it3); y3=cadd_(t1,it3); }
}

template<bool INV>
__device__ __forceinline__ void dft8ip_(cplx* v){
  cplx e0,e1,e2,e3,o0,o1,o2,o3;
  dft4_<INV>(v[0],v[2],v[4],v[6], e0,e1,e2,e3);
  dft4_<INV>(v[1],v[3],v[5],v[7], o0,o1,o2,o3);
  const float r = 0.70710678118654752440f;
  cplx w1 = INV ? make_float2(r, r)    : make_float2(r,-r);
  cplx w2 = INV ? make_float2(0.f,1.f) : make_float2(0.f,-1.f);
  cplx w3 = INV ? make_float2(-r,r)    : make_float2(-r,-r);
  cplx t1 = cmul_(o1,w1), t2 = cmul_(o2,w2), t3 = cmul_(o3,w3);
  v[0]=cadd_(e0,o0); v[4]=csub_(e0,o0);
  v[1]=cadd_(e1,t1); v[5]=csub_(e1,t1);
  v[2]=cadd_(e2,t2); v[6]=csub_(e2,t2);
  v[3]=cadd_(e3,t3); v[7]=csub_(e3,t3);
}

template<bool INV>
__device__ __forceinline__ void dft16ip_(cplx* v){
  cplx t0[4], t1[4], t2[4], t3[4];
  dft4_<INV>(v[0], v[4], v[8],  v[12], t0[0],t0[1],t0[2],t0[3]);
  dft4_<INV>(v[1], v[5], v[9],  v[13], t1[0],t1[1],t1[2],t1[3]);
  dft4_<INV>(v[2], v[6], v[10], v[14], t2[0],t2[1],t2[2],t2[3]);
  dft4_<INV>(v[3], v[7], v[11], v[15], t3[0],t3[1],t3[2],t3[3]);
  const float C1=0.92387953251128675613f, S1=0.38268343236508977172f, R2=0.70710678118654752440f;
  #define TWD_(x, cc, ss) (INV ? cmul_((x), make_float2((cc), (ss))) : cmul_((x), make_float2((cc), -(ss))))
  t1[1] = TWD_(t1[1], C1, S1);
  t1[2] = TWD_(t1[2], R2, R2);
  t1[3] = TWD_(t1[3], S1, C1);
  t2[1] = TWD_(t2[1], R2, R2);
  t2[2] = TWD_(t2[2], 0.f, 1.f);
  t2[3] = TWD_(t2[3], -R2, R2);
  t3[1] = TWD_(t3[1], S1, C1);
  t3[2] = TWD_(t3[2], -R2, R2);
  t3[3] = TWD_(t3[3], -C1, -S1);
  #undef TWD_
  dft4_<INV>(t0[0], t1[0], t2[0], t3[0], v[0], v[4], v[8],  v[12]);
  dft4_<INV>(t0[1], t1[1], t2[1], t3[1], v[1], v[5], v[9],  v[13]);
  dft4_<INV>(t0[2], t1[2], t2[2], t3[2], v[2], v[6], v[10], v[14]);
  dft4_<INV>(t0[3], t1[3], t2[3], t3[3], v[3], v[7], v[11], v[15]);
}

template<int R0, bool INV>
__device__ __forceinline__ void fft_core(float* lre, float* lim, int t){
  constexpr int Q = R0/16;
  constexpr int S1 = R0 + 8;
  int g = t >> 4, a = t & 15;
  cplx v[Q];
  #pragma unroll
  for (int bb=0;bb<Q;bb++){ int idx = g*S1 + a + 16*bb; v[bb]=make_float2(lre[idx],lim[idx]); }
  if constexpr (Q==16) dft16ip_<INV>(v); else dft8ip_<INV>(v);
  float th = (INV?TWO_PI_F:-TWO_PI_F)*(float)a/(float)R0;
  float sn,cs; __sincosf(th,&sn,&cs);
  cplx w1=make_float2(cs,sn), wu=w1;
  #pragma unroll
  for (int c=1;c<Q;c++){ v[c]=cmul_(v[c],wu); wu=cmul_(wu,w1); }
  __syncthreads();
  #pragma unroll
  for (int c=0;c<Q;c++){ int m = a*Q + ((c+a)&(Q-1)); lre[g*S1+m]=v[c].x; lim[g*S1+m]=v[c].y; }
  __syncthreads();
}

template<int R0, bool INV>
__device__ __forceinline__ bool fft_stage2(const float* lre, const float* lim, int t, int& g2, int& c2, cplx* z){
  constexpr int Q = R0/16; constexpr int S1 = R0+8;
  bool active = (R0==256) || (t < 16*Q);
  g2 = (R0==256)?(t>>4):(t>>3);
  c2 = (R0==256)?(t&15):(t&7);
  if (active){
    #pragma unroll
    for (int a2=0;a2<16;a2++){ int m = a2*Q + ((c2+a2)&(Q-1)); z[a2]=make_float2(lre[g2*S1+m], lim[g2*S1+m]); }
    dft16ip_<INV>(z);
  }
  return active;
}

// ---------------- noise fwd pass1 with fused pack; bf16-packed output ----------------
__global__ __launch_bounds__(256) void k_fft_pack_fwd1(const float* __restrict__ noise, unsigned int* __restrict__ dst, float interBase){
  constexpr int Q=16, S1=264;
  __shared__ float lre[4352], lim[4352];
  int t=threadIdx.x;
  int bx=blockIdx.x;
  int sig = bx>>3;
  int tBase=(bx&7)*16;
  const float* n0 = noise + (size_t)(2*sig)*NSAMP;
  const float* n1 = noise + (size_t)(2*sig+1)*NSAMP;
  #pragma unroll
  for (int i=0;i<16;i++){
    int e=t+256*i, g=e&15, r=e>>4;
    int ts = tBase+g+128*r;
    lre[g*S1+r]=n0[ts]*2.f-1.f;
    lim[g*S1+r]=n1[ts]*2.f-1.f;
  }
  __syncthreads();
  fft_core<256,false>(lre,lim,t);
  int g2,c2; cplx z[16];
  fft_stage2<256,false>(lre,lim,t,g2,c2,z);
  int p=tBase+g2;
  float thp=interBase*(float)p;
  float snc,csc; __sincosf(thp*(float)c2,&snc,&csc);
  float sns,css; __sincosf(thp*(float)Q,&sns,&css);
  cplx wu=make_float2(csc,snc), ws=make_float2(css,sns);
  unsigned int* db = dst + (size_t)sig*NSAMP;
  size_t ob=(size_t)256*(size_t)p+(size_t)c2;
  #pragma unroll
  for (int d=0;d<16;d++){
    cplx val = cmul_(z[d],wu);
    db[ob+(size_t)(d*16)] = packbf2(val.x, val.y);
    wu=cmul_(wu,ws);
  }
}

// ---------------- noise fwd pass2 + filter + inverse pass1, all fused (bf16 input) ----------------
__device__ __forceinline__ void fft128_natural(float* re, float* im, int t){
  __syncthreads();
  fft_core<128,false>(re,im,t);
  int g2,c2; cplx z[16];
  bool act = fft_stage2<128,false>(re,im,t,g2,c2,z);
  __syncthreads();
  if (act){
    #pragma unroll
    for (int d=0;d<16;d++){ int u=c2+8*d; re[u*17+g2]=z[d].x; im[u*17+g2]=z[d].y; }
  }
  __syncthreads();
}

__global__ __launch_bounds__(256) void k_nfilter_ip1(const unsigned int* __restrict__ src, cplx* __restrict__ dst,
    const float* __restrict__ P){
  __shared__ float aRe[2176], aIm[2176], bRe[2176], bIm[2176];
  __shared__ float fRe[2176], fIm[2176];
  __shared__ float c1s[16], c2sh[16];
  int t=threadIdx.x, pb=blockIdx.x, j=blockIdx.y;
  const unsigned int* sb = src + ((size_t)j<<15);
  cplx* db = dst + ((size_t)j<<15);
  if (t<16) c1s[t] = P[(size_t)(2*j)*PSTRIDE+28+t];
  else if (t<32) c2sh[t-16] = P[(size_t)(2*j+1)*PSTRIDE+28+(t-16)];
  #pragma unroll
  for (int i=0;i<8;i++){
    int e=t+256*i, g=e&15, r=e>>4;
    int col = (pb<8)? (pb*16+g) : (g*16);
    unsigned int u = sb[col + (r<<8)];
    aRe[g*136+r]=ubf_lo(u); aIm[g*136+r]=ubf_hi(u);
  }
  fft128_natural(aRe,aIm,t);
  if (pb<8){
    #pragma unroll
    for (int i=0;i<8;i++){
      int e=t+256*i, g=e&15, r=e>>4;
      int col = 240-pb*16+g;
      unsigned int u = sb[col + (r<<8)];
      bRe[g*136+r]=ubf_lo(u); bIm[g*136+r]=ubf_hi(u);
    }
    fft128_natural(bRe,bIm,t);
  }
  const float inv32768 = 1.0f/32768.0f;
  if (pb<8){
    for (int s=0;s<2;s++){
      __syncthreads();
      #pragma unroll
      for (int uu=0; uu<8; uu++){
        int g=t&15, u=(t>>4)+16*uu;
        if (g!=0){
          int colK = s? (240-pb*16+g) : (pb*16+g);
          int gm=16-g, um=127-u;
          float Zkx,Zky,Zmx,Zmy;
          if (s==0){ Zkx=aRe[u*17+g]; Zky=aIm[u*17+g]; Zmx=bRe[um*17+gm]; Zmy=bIm[um*17+gm]; }
          else     { Zkx=bRe[u*17+g]; Zky=bIm[u*17+g]; Zmx=aRe[um*17+gm]; Zmy=aIm[um*17+gm]; }
          int k = colK + (u<<8);
          int kb = min(k, NSAMP-k);
          float coords=fminf(fmaxf((kb+0.5f)*(16.0f/16385.0f)-0.5f,0.0f),15.0f);
          int lo=(int)coords; float w=coords-lo; int hi=min(lo+1,15);
          float s1=(c1s[lo]+w*(c1s[hi]-c1s[lo]))*inv32768;
          float s2=(c2sh[lo]+w*(c2sh[hi]-c2sh[lo]))*inv32768;
          float U1x=0.5f*(Zkx+Zmx), U1y=0.5f*(Zky-Zmy);
          float U2x=0.5f*(Zky+Zmy), U2y=-0.5f*(Zkx-Zmx);
          fRe[g*136+u]=U1x*s1 - U2y*s2; fIm[g*136+u]=U1y*s1 + U2x*s2;
        }
      }
      __syncthreads();
      fft_core<128,true>(fRe,fIm,t);
      int gg,cc; cplx z[16];
      bool act = fft_stage2<128,true>(fRe,fIm,t,gg,cc,z);
      if (act && gg!=0){
        int p = (s==0) ? (pb*16+gg) : (240-pb*16+gg);
        float thp=(TWO_PI_F/32768.0f)*(float)p;
        float snc,csc; __sincosf(thp*(float)cc,&snc,&csc);
        float sns,css; __sincosf(thp*8.0f,&sns,&css);
        cplx wu=make_float2(csc,snc), wsx=make_float2(css,sns);
        int ob=128*p+cc;
        #pragma unroll
        for (int d=0;d<16;d++){ db[ob+8*d]=cmul_(z[d],wu); wu=cmul_(wu,wsx); }
      }
    }
  } else {
    __syncthreads();
    #pragma unroll
    for (int uu=0; uu<8; uu++){
      int g=t&15, u=(t>>4)+16*uu;
      int k = g*16 + (u<<8);
      int gm=(16-g)&15;
      int um=(g==0)? ((128-u)&127) : (127-u);
      float Zkx=aRe[u*17+g], Zky=aIm[u*17+g];
      float Zmx=aRe[um*17+gm], Zmy=aIm[um*17+gm];
      int kb = min(k, NSAMP-k);
      float coords=fminf(fmaxf((kb+0.5f)*(16.0f/16385.0f)-0.5f,0.0f),15.0f);
      int lo=(int)coords; float w=coords-lo; int hi=min(lo+1,15);
      float s1=(c1s[lo]+w*(c1s[hi]-c1s[lo]))*inv32768;
      float s2=(c2sh[lo]+w*(c2sh[hi]-c2sh[lo]))*inv32768;
      float U1x=0.5f*(Zkx+Zmx), U1y=0.5f*(Zky-Zmy);
      float U2x=0.5f*(Zky+Zmy), U2y=-0.5f*(Zkx-Zmx);
      fRe[g*136+u]=U1x*s1 - U2y*s2; fIm[g*136+u]=U1y*s1 + U2x*s2;
    }
    __syncthreads();
    fft_core<128,true>(fRe,fIm,t);
    int gg,cc; cplx z[16];
    bool act = fft_stage2<128,true>(fRe,fIm,t,gg,cc,z);
    if (act){
      int p = 16*gg;
      float thp=(TWO_PI_F/32768.0f)*(float)p;
      float snc,csc; __sincosf(thp*(float)cc,&snc,&csc);
      float sns,css; __sincosf(thp*8.0f,&sns,&css);
      cplx wu=make_float2(csc,snc), wsx=make_float2(css,sns);
      int ob=128*p+cc;
      #pragma unroll
      for (int d=0;d<16;d++){ db[ob+8*d]=cmul_(z[d],wu); wu=cmul_(wu,wsx); }
    }
  }
}

// ---------------- noise inverse final with split-plane bf16 store ----------------
__global__ __launch_bounds__(256) void k_ifinal_split(const cplx* __restrict__ src, unsigned short* __restrict__ dsth){
  constexpr int S1=264;
  __shared__ float lre[4352], lim[4352];
  int t=threadIdx.x; int bx=blockIdx.x;
  int sig=bx>>3; int tBase=(bx&7)*16;
  const cplx* sb = src + (size_t)sig*NSAMP;
  #pragma unroll
  for (int i=0;i<16;i++){
    int e=t+256*i, g=e&15, r=e>>4;
    cplx vv = sb[tBase+g + (size_t)r*128];
    lre[g*S1+r]=vv.x; lim[g*S1+r]=vv.y;
  }
  __syncthreads();
  fft_core<256,true>(lre,lim,t);
  int g2,c2; cplx z[16];
  fft_stage2<256,true>(lre,lim,t,g2,c2,z);
  __syncthreads();
  #pragma unroll
  for (int d=0;d<16;d++){ int u=c2+16*d; lre[u*17+g2]=z[d].x; lim[u*17+g2]=z[d].y; }
  __syncthreads();
  unsigned short* p0 = dsth + (size_t)(2*sig)*NSAMP;
  unsigned short* p1 = dsth + (size_t)(2*sig+1)*NSAMP;
  #pragma unroll
  for (int i=0;i<16;i++){
    int e=t+256*i, g3=e&15, u=e>>4;
    int ts = tBase+g3+u*128;
    p0[ts]=packbf1(lre[u*17+g3]); p1[ts]=packbf1(lim[u*17+g3]);
  }
}

// ---------------- conv fwd pass1 with fused build (LDS overlay); bf16 in & out ----------------
__global__ __launch_bounds__(256) void k_conv_build_fwd1(const float* __restrict__ P,
    const unsigned short* __restrict__ NZh, unsigned int* __restrict__ dst, int rowBase, float interBase){
  constexpr int Q=16, S1=264;
  __shared__ float smem[8448];
  float* lre = smem;
  float* lim = smem + 4224;
  float* sTab = smem;
  int t=threadIdx.x;
  int row = rowBase + blockIdx.y;
  int tBase = blockIdx.x*16;
  const float* Pr = P + (size_t)row*PSTRIDE;
  for (int i=t; i<P_END; i+=256) sTab[i] = Pr[i];
  __syncthreads();
  float mu=sTab[0], sigma=sTab[1], amp=sTab[2], pscale=sTab[3];
  float fac[8], mh[8];
  #pragma unroll
  for (int h=0;h<8;h++){ fac[h]=sTab[4+h]; mh[h]=sTab[12+h]; }
  const float2* fe2 = (const float2*)&sTab[P_FEPAIR];
  const float*  pw2 = &sTab[P_PW2];
  const float2* LQt = (const float2*)&sTab[P_LQ];
  const float*  Af  = &sTab[P_AF];
  const unsigned short* nzrow = NZh + (size_t)row*NSAMP;
  float vre[8], vim[8];
  #pragma unroll
  for (int i=0;i<8;i++){
    int e=t+256*i, g=e&15, r=e>>4;
    int ts = tBase + g + (r<<8);
    float cc=fminf(fmaxf((ts+0.5f)*(1.0f/256.0f)-0.5f,0.0f),127.0f);
    int lo=(int)cc; float w=cc-lo;
    float2 fp = fe2[lo];
    float fev = fp.x + w*fp.y;
    int slot, n0;
    if (ts<128){ slot=0; n0=ts+1; } else { int km=(ts-128)>>8; slot=km+1; n0=ts-127-(km<<8); }
    float nf=(float)n0, nf2=nf*nf;
    float2 lq = LQt[slot];
    float base = nf*lq.x + nf2*lq.y;
    float wm = (lo<127)? w : 0.0f;
    float resv=0.f;
    #pragma unroll
    for (int h=0;h<8;h++){
      float mgb = pw2[h*128+lo];
      if (mgb > 1e-7f){
        float rr = Af[slot*8+h] + fac[h]*base;
        float fr = rr - floorf(rr);
        float s = __builtin_amdgcn_sinf(fr);
        resv += s*mgb*(1.0f + wm*(mh[h]-1.0f));
      }
    }
    float zz=((float)ts-mu)/sigma;
    float prb=pscale*__expf(-0.5f*zz*zz);
    vre[i] = prb*unpackbf1(nzrow[ts])*amp*fev;
    vim[i] = resv;
  }
  __syncthreads();
  #pragma unroll
  for (int i=0;i<8;i++){
    int e=t+256*i, g=e&15, r=e>>4;
    lre[g*S1+r]=vre[i]; lim[g*S1+r]=vim[i];
  }
  #pragma unroll
  for (int i=8;i<16;i++){
    int e=t+256*i, g=e&15, r=e>>4;
    lre[g*S1+r]=0.f; lim[g*S1+r]=0.f;
  }
  __syncthreads();
  fft_core<256,false>(lre,lim,t);
  int g2,c2; cplx z[16];
  fft_stage2<256,false>(lre,lim,t,g2,c2,z);
  int p = tBase+g2;
  float thp = interBase*(float)p;
  float snc,csc; __sincosf(thp*(float)c2,&snc,&csc);
  float sns,css; __sincosf(thp*(float)Q,&sns,&css);
  cplx wu=make_float2(csc,snc), ws=make_float2(css,sns);
  unsigned int* db = dst + (size_t)blockIdx.y*NFFT2;
  size_t ob=(size_t)256*(size_t)p+(size_t)c2;
  #pragma unroll
  for (int d=0; d<16; d++){
    cplx val = cmul_(z[d],wu);
    db[ob+(size_t)(d*16)] = packbf2(val.x, val.y);
    wu=cmul_(wu,ws);
  }
}

// ---------------- fused: conv fwd pass2 + Z^2 accumulate (4 events) + inverse pass1; bf16 E ----------------
// grid (16 colgroups, bpc batches, 2 halves).
__global__ __launch_bounds__(256) void k_sq_inv1(const unsigned int* __restrict__ C,
    unsigned int* __restrict__ E, int bpc){
  constexpr int Q=16, S1=264;
  __shared__ float lre[4352], lim[4352];
  int t=threadIdx.x;
  int tBase = blockIdx.x*16;
  int bLoc = blockIdx.y;
  int half = blockIdx.z;
  float accx[16], accy[16];
  #pragma unroll
  for (int d=0;d<16;d++){ accx[d]=0.f; accy[d]=0.f; }
  int g2=t>>4, c2=t&15;
  for (int e=0;e<4;e++){
    int sigLoc = bLoc*8 + half*4 + e;
    const unsigned int* sb = C + (size_t)sigLoc*NFFT2;
    __syncthreads();
    #pragma unroll
    for (int i=0;i<16;i++){
      int ee=t+256*i, g=ee&15, r=ee>>4;
      unsigned int u = sb[tBase+g + (size_t)r*256];
      lre[g*S1+r]=ubf_lo(u);
      lim[g*S1+r]=ubf_hi(u);
    }
    __syncthreads();
    fft_core<256,false>(lre,lim,t);
    int gg,cc; cplx z[16];
    fft_stage2<256,false>(lre,lim,t,gg,cc,z);
    #pragma unroll
    for (int d=0;d<16;d++){
      float x=z[d].x, y=z[d].y;
      accx[d] += x*x - y*y;
      accy[d] += 2.f*x*y;
    }
  }
  __syncthreads();
  const float s = 1.0f/131072.0f;
  #pragma unroll
  for (int d=0;d<16;d++){
    int rrow = c2 + 16*d;
    lre[g2*S1+rrow] = accx[d]*s;
    lim[g2*S1+rrow] = accy[d]*s;
  }
  __syncthreads();
  fft_core<256,true>(lre,lim,t);
  int gg,cc; cplx z[16];
  fft_stage2<256,true>(lre,lim,t,gg,cc,z);
  int p = tBase+gg;
  float thp = (TWO_PI_F/65536.0f)*(float)p;
  float snc,csc; __sincosf(thp*(float)cc,&snc,&csc);
  float sns,css; __sincosf(thp*(float)Q,&sns,&css);
  cplx wu=make_float2(csc,snc), ws=make_float2(css,sns);
  unsigned int* db = E + ((size_t)half*bpc + bLoc)*NFFT2;
  size_t ob=(size_t)256*(size_t)p+(size_t)cc;
  #pragma unroll
  for (int d=0; d<16; d++){
    cplx val = cmul_(z[d],wu);
    db[ob+(size_t)(d*16)] = packbf2(val.x, val.y);
    wu=cmul_(wu,ws);
  }
}

// ---------------- conv inverse final: sum 2 bf16 partials, keep Im, write to out ----------------
__global__ __launch_bounds__(256) void k_final_imout(const unsigned int* __restrict__ E,
    float* __restrict__ out, int batchBase, int bpc){
  constexpr int S1=264;
  __shared__ float lre[4352], lim[4352];
  int t=threadIdx.x; int bx=blockIdx.x;
  int sig=bx>>4; int tBase=(bx&15)*16;
  const unsigned int* s0 = E + (size_t)sig*NFFT2;
  size_t hstride = (size_t)bpc*NFFT2;
  #pragma unroll
  for (int i=0;i<16;i++){
    int e=t+256*i, g=e&15, r=e>>4;
    size_t idx = tBase+g+(size_t)r*256;
    unsigned int u0=s0[idx], u1=s0[hstride+idx];
    lre[g*S1+r]=ubf_lo(u0)+ubf_lo(u1);
    lim[g*S1+r]=ubf_hi(u0)+ubf_hi(u1);
  }
  __syncthreads();
  fft_core<256,true>(lre,lim,t);
  int g2,c2; cplx z[16];
  fft_stage2<256,true>(lre,lim,t,g2,c2,z);
  __syncthreads();
  #pragma unroll
  for (int d=0;d<16;d++){ int u=c2+16*d; lre[u*17+g2]=z[d].y; }   // Im only
  __syncthreads();
  float* o = out + (size_t)(batchBase+sig)*NSAMP;
  #pragma unroll
  for (int i=0;i<8;i++){
    int e=t+256*i, g3=e&15, u=e>>4;
    o[tBase+g3 + u*256] = lre[u*17+g3];
  }
}

// ---------------- parameter extraction + ALL per-row tables ----------------
__global__ __launch_bounds__(256) void k_params(const float* __restrict__ x, float* __restrict__ P){
  int row = blockIdx.x; int t = threadIdx.x;
  const float* xr = x + row*428;
  float* Pr = P + (size_t)row*PSTRIDE;
  __shared__ float sx[428];
  __shared__ float fes[128], f0s[128];
  __shared__ double Cds[128];
  __shared__ float facs[8], ms[8], afs[8];
  __shared__ float f0_sh;
  for (int i=t;i<428;i+=256) sx[i]=1.0f/(1.0f+expf(-xr[i]));
  __syncthreads();
  if (t==0){
    float mean = sx[0]; float stds = sx[1]*0.1f; float amp = sx[2]*sx[2];
    float mu = fminf(fmaxf(mean*32768.0f, -16384.0f), 49152.0f);
    float sigma = fminf(fmaxf((1e-8f + stds)*32768.0f, 0.0f), 32767.0f);
    float c = 1.0f/(sigma*2.5066282746310002f);
    float tt0 = fminf(fmaxf(floorf(mu), 0.0f), 32767.0f);
    float tt1 = fminf(fmaxf(ceilf(mu), 0.0f), 32767.0f);
    float z0 = (tt0-mu)/sigma, z1=(tt1-mu)/sigma;
    float gmax = fmaxf(expf(-0.5f*z0*z0), expf(-0.5f*z1*z1));
    float pscale = c / (c*gmax + 1e-12f);
    Pr[0]=mu; Pr[1]=sigma; Pr[2]=amp; Pr[3]=pscale;
  }
  if (t<8){
    float fv = (t==0)?1.0f:(1.0f+sx[4+t]*7.0f);
    facs[t]=fv; Pr[4+t]=fv;
    float m = sx[12+t]*0.9999f; m=m*m; ms[t]=m; Pr[12+t]=m;
    afs[t]=sx[164+t]*sx[164+t];
  }
  if (t>=32&&t<48) Pr[28+(t-32)] = sx[20+(t-32)];
  if (t==64) f0_sh = sx[3]*sx[3];
  if (t==65){
    float acc=0.f;
    for (int f=0;f<128;f++){ acc += sx[36+f]*2.0f-1.0f; fes[f]=fminf(fmaxf(acc,0.f),1.f); }
  }
  __syncthreads();
  if (t<128){
    float f0=f0_sh;
    f0s[t] = f0 + sx[172+t]*(f0*0.01f);
  }
  __syncthreads();
  if (t==0){
    double acc = 128.0*(double)f0s[0]; Cds[0]=acc;
    for (int k=0;k<127;k++){ acc += 128.0*((double)f0s[k]+(double)f0s[k+1]); Cds[k+1]=acc; }
  }
  if (t<128){
    float v=fes[t], vh=fes[min(t+1,127)];
    Pr[P_FEPAIR+2*t]=v; Pr[P_FEPAIR+2*t+1]=vh-v;
  }
  if (t>=128 && t<136){
    int h=t-128; float m=ms[h];
    float acc = afs[h]*m;
    float* dstp = Pr + P_PW2 + h*128;
    dstp[0]=acc;
    for (int f=1;f<128;f++){ acc*=m; dstp[f]=acc; }
  }
  __syncthreads();
  const double MINF_D=20.0/11025.0, FSPAN_D=2980.0/11025.0;
  if (t<129){
    int k=t-1;
    float Lb, Qb;
    if (k<0){ Lb=(float)(0.5*(MINF_D+FSPAN_D*(double)f0s[0])); Qb=0.f; }
    else {
      double f0k=(double)f0s[k];
      double d=(k<127)?((double)f0s[k+1]-f0k):0.0;
      Lb=(float)(0.5*(MINF_D+FSPAN_D*f0k));
      Qb=(float)(0.5*FSPAN_D*d*(1.0/512.0));
    }
    Pr[P_LQ+2*t]=Lb; Pr[P_LQ+2*t+1]=Qb;
  }
  for (int idx=t; idx<129*8; idx+=256){
    int jj=idx>>3, h=idx&7, k=jj-1;
    float Aval;
    if (k<0) Aval=0.f;
    else {
      double phi0=(double)(128+256*k)*MINF_D+FSPAN_D*Cds[k];
      Aval=(float)(0.5*fmod((double)facs[h]*phi0,2.0));
    }
    Pr[P_AF+idx]=Aval;
  }
}

// ---------------- host ----------------
extern "C" void kernel_launch(void* const* d_in, const int* in_sizes, int n_in,
                              void* d_out, int out_size, void* d_ws, size_t ws_size,
                              hipStream_t stream){
  const float* x = (const float*)d_in[0];
  const float* noise = (const float*)d_in[1];
  float* out = (float*)d_out;
  char* ws = (char*)d_ws;

  const size_t szA = (size_t)64*NSAMP*sizeof(unsigned int);   // 8.4 MB (bf16 cplx spectra / nz planes)
  const size_t szB = (size_t)64*NSAMP*sizeof(cplx);           // 16.8 MB
  const size_t szE = (size_t)2*16*NFFT2*sizeof(unsigned int); // 8.4 MB (2 halves, max bpc=16)
  const size_t oA  = (size_t)2<<20;
  const size_t oB  = oA + szA;
  const size_t oE  = oB + szB;
  const size_t oC  = oE + szE;

  const int cand[5] = {1,2,4,8,16};
  int nchunk = -1;
  for (int ci=0; ci<5; ci++){
    size_t csz = ((size_t)(128/cand[ci]))*NFFT2*sizeof(unsigned int);
    if (oC + csz <= ws_size){ nchunk = cand[ci]; break; }
  }
  if (nchunk < 0) return;
  int sigPerChunk = 128/nchunk;
  int bpc = sigPerChunk/8;

  float* P = (float*)(ws);
  unsigned int* A = (unsigned int*)(ws + oA);
  cplx* B = (cplx*)(ws + oB);
  unsigned int* E = (unsigned int*)(ws + oE);
  unsigned int* C = (unsigned int*)(ws + oC);

  k_params<<<128, 256, 0, stream>>>(x, P);
  // noise: pack+pass1 -> A(bf16); pass2+filter+ipass1 -> B; final+split -> A (bf16 planes)
  k_fft_pack_fwd1<<<512, 256, 0, stream>>>(noise, A, -TWO_PI_F/32768.0f);
  k_nfilter_ip1<<<dim3(9,64), 256, 0, stream>>>(A, B, P);
  k_ifinal_split<<<512, 256, 0, stream>>>(B, (unsigned short*)A);

  for (int c=0; c<nchunk; c++){
    int rowBase = c*sigPerChunk;
    int batchBase = c*bpc;
    k_conv_build_fwd1<<<dim3(16, sigPerChunk), 256, 0, stream>>>(P, (unsigned short*)A, C, rowBase, -TWO_PI_F/65536.0f);
    k_sq_inv1<<<dim3(16, bpc, 2), 256, 0, stream>>>(C, E, bpc);
    k_final_imout<<<bpc*16, 256, 0, stream>>>(E, out, batchBase, bpc);
  }
}